// Round 3
// baseline (145.460 us; speedup 1.0000x reference)
//
#include <hip/hip_runtime.h>

// Problem constants (fixed by setup_inputs)
#define B_   16
#define T_   2048
#define F_   64
#define A_   48
#define TOK  64              // tokens per block (4 waves x 16 tokens)
#define WSTR 68              // fp32 window row stride (floats)
#define HWS  72              // f16 window row stride (halves): 144B, 8B-aligned
#define SSTR 49              // score row stride (floats)
#define NWIN 111             // window rows: t0-48 .. t0+62

typedef __attribute__((ext_vector_type(4))) _Float16 half4;  // MFMA 16x16x16 A/B frag
typedef __attribute__((ext_vector_type(2))) _Float16 h2;     // packed f16 pair
typedef __attribute__((ext_vector_type(2))) unsigned short us2;
typedef __attribute__((ext_vector_type(4))) float    f32x4;  // MFMA C/D frag

#define LOG2E 1.4426950408889634f

__device__ __forceinline__ h2 h2splat(float x) {
    _Float16 h = (_Float16)x; h2 r; r[0] = h; r[1] = h; return r;
}

// ---- trans-free sigmoid, packed f16: sigma = 1/(1+2^c), c = -log2e * x
// (W pre-scaled by -log2e so the MFMA result IS c).
// 2^c: i = rne(c) via +1536 magic-add (f16 ulp=1 at 1536); 2^f by deg-4
// Taylor (f in [-0.5,0.5], trunc err 5e-5); 2^i bit-built from the magic
// value's mantissa. 1/(1+e): bit-trick seed + 2 Newton steps.
// c clamped to +-14.4375: keeps y=1+e <= ~23200 (seed stays valid, no NaN),
// saturation tails cost < 6e-5 absolute.
__device__ __forceinline__ h2 sig2(float a, float b) {
    h2 c = __builtin_bit_cast(h2, __builtin_amdgcn_cvt_pkrtz(a, b));
    const h2 CLO = h2splat(-14.4375f), CHI = h2splat(14.4375f);
    c = __builtin_elementwise_min(__builtin_elementwise_max(c, CLO), CHI);
    const h2 BIG = h2splat(1536.0f);
    h2 v  = c + BIG;                 // rne(c) + 1536, exact int in f16
    h2 fi = v - BIG;                 // i as f16 (exact)
    h2 f  = c - fi;                  // f in [-0.5, 0.5], exact
    const h2 L1 = h2splat(0.69314718f), L2 = h2splat(0.24022651f),
             L3 = h2splat(0.05550411f), L4 = h2splat(0.00961813f);
    const h2 ONE = h2splat(1.0f), TWO = h2splat(2.0f);
    h2 p = __builtin_elementwise_fma(f, L4, L3);
    p = __builtin_elementwise_fma(f, p, L2);
    p = __builtin_elementwise_fma(f, p, L1);
    p = __builtin_elementwise_fma(f, p, ONE);          // p = 2^f
    us2 vb = __builtin_bit_cast(us2, v);
    us2 tb = vb - (us2){0x65F1, 0x65F1};               // = i + 15
    us2 sb = tb << (us2){10, 10};                      // f16 bits of 2^i
    h2 e = p * __builtin_bit_cast(h2, sb);             // 2^c
    h2 y = e + ONE;
    us2 yb = __builtin_bit_cast(us2, y);
    us2 rb = (us2){0x7799, 0x7799} - yb;               // ~1/y seed (+-6%)
    h2 r = __builtin_bit_cast(h2, rb);
    r = r * __builtin_elementwise_fma(-y, r, TWO);     // Newton 1
    r = r * __builtin_elementwise_fma(-y, r, TWO);     // Newton 2
    return r;                                          // sigma
}

__device__ __forceinline__ half4 sigpack(f32x4 c) {
    h2 lo = sig2(c[0], c[1]);
    h2 hi = sig2(c[2], c[3]);
    half4 h; h[0] = lo[0]; h[1] = lo[1]; h[2] = hi[0]; h[3] = hi[1];
    return h;
}

__device__ __forceinline__ h2 pk2(float a, float b) {
    return __builtin_bit_cast(h2, __builtin_amdgcn_cvt_pkrtz(a, b));
}

// 4x4 MFMA sweep: c[mo] = A[mo][:] x hb (K=64 via 4 chained 16x16x16)
__device__ __forceinline__ void gemm4(const half4 (&aW)[4][4], const half4 (&hb)[4], f32x4 (&c)[4]) {
#pragma unroll
    for (int mo = 0; mo < 4; ++mo) {
        f32x4 z = {0.f, 0.f, 0.f, 0.f};
#pragma unroll
        for (int kt = 0; kt < 4; ++kt)
            z = __builtin_amdgcn_mfma_f32_16x16x16f16(aW[mo][kt], hb[kt], z, 0, 0, 0);
        c[mo] = z;
    }
}

// Shared allocation hoisted to the kernel so both template instantiations
// share ONE 58.8 KB block.
struct Smem {
    float    sWin[NWIN * WSTR];    // 30.2 KB fp32 window (epilogue)
    _Float16 sWinH[NWIN * HWS];    // 16.0 KB f16 window (score B-frags)
    float    sSc[TOK * SSTR];      // 12.5 KB scores
};

// FIRST = block contains tokens 0..63 (needs clamping + validity masks).
template<bool FIRST>
__device__ __forceinline__ void run_block(Smem& sm, int b, int t0,
                                          const float* __restrict__ he,
                                          const float* __restrict__ W1,
                                          const float* __restrict__ W2,
                                          float* __restrict__ out)
{
    const int tid = threadIdx.x;
    const float* __restrict__ heB = he + (size_t)b * T_ * F_;

    // ---- stage window rows: fp32 + f16 copies. Rows with g<0 never read.
    for (int i = tid; i < NWIN * 16; i += 256) {
        int row = i >> 4, c4 = (i & 15) * 4;
        int g = t0 - 48 + row;
        if (!FIRST || g >= 0) {
            float4 v = *(const float4*)(heB + (size_t)g * F_ + c4);
            *(float4*)(&sm.sWin[row * WSTR + c4]) = v;
            h2 lo = pk2(v.x, v.y), hi = pk2(v.z, v.w);
            half4 h; h[0] = lo[0]; h[1] = lo[1]; h[2] = hi[0]; h[3] = hi[1];
            *(half4*)(&sm.sWinH[row * HWS + c4]) = h;
        }
    }

    const int lane = tid & 63;
    const int wv   = tid >> 6;          // wave owns tokens wv*16 .. wv*16+15
    const int quad = lane >> 4;
    const int ml   = lane & 15;
    const int tw0  = wv * 16;
    const int tg   = t0 + tw0 + ml;     // this lane's token
    const int L    = min(A_, max(tg, 1));

    // ---- A-operand = (-log2e * W^T) fragments, registers for the whole loop.
    half4 aW1[4][4], aW2[4][4];         // [mo][kt]
    for (int mo = 0; mo < 4; ++mo)
        for (int kt = 0; kt < 4; ++kt) {
            half4 f1, f2;
#pragma unroll
            for (int j = 0; j < 4; ++j) {
                int k = kt * 16 + quad * 4 + j;
                f1[j] = (_Float16)(-LOG2E * W1[k * F_ + mo * 16 + ml]);
                f2[j] = (_Float16)(-LOG2E * W2[k * F_ + mo * 16 + ml]);
            }
            aW1[mo][kt] = f1; aW2[mo][kt] = f2;
        }

    // ---- H state as B-frags: hb[kt] = H[token=ml][kt*16+quad*4+j], f16.
    half4 hb[4];
#pragma unroll
    for (int kt = 0; kt < 4; ++kt) {
        float4 v = *(const float4*)(heB + (size_t)tg * F_ + kt * 16 + quad * 4);
        half4 h;
        h[0] = (_Float16)v.x; h[1] = (_Float16)v.y;
        h[2] = (_Float16)v.z; h[3] = (_Float16)v.w;
        hb[kt] = h;
    }

    // ---- prologue GEMM1 (pure register work, overlaps the staging barrier)
    f32x4 c1[4];
    gemm4(aW1, hb, c1);

    __syncthreads();

    // Diagonal-owner predicate for the score MFMA: lane holds C[t][t] for
    // t = ml iff quad == ml>>2. Loop-invariant.
    const bool amDiag = (quad == (ml >> 2));
    const bool s0 = (ml & 3) == 0, s1 = (ml & 3) == 1, s2 = (ml & 3) == 2;
    float* scp = &sm.sSc[(tw0 + ml) * SSTR];

    // f16 window base for this lane (fast path: row for step a is tw0+ml+a).
    const _Float16* __restrict__ wbase = &sm.sWinH[(tw0 + ml) * HWS + quad * 4];

    // score B-frag pointer for step a2
    auto wp_for = [&](int a2) -> const _Float16* {
        if (FIRST) {
            int j = tg - L + a2; if (j < 0) j = 0;
            return &sm.sWinH[(j + 48) * HWS + quad * 4];
        }
        return wbase + a2 * HWS;
    };

    // g regs for step a=0
    half4 g0, g1, g2, g3;
    {
        const _Float16* wp = wp_for(0);
        g0 = *(const half4*)(wp);
        g1 = *(const half4*)(wp + 16);
        g2 = *(const half4*)(wp + 32);
        g3 = *(const half4*)(wp + 48);
    }

    // ---- 48-step recurrence, software-pipelined (R1 structure, kept):
#pragma unroll 4
    for (int a = 0; a < A_; ++a) {
        // H_new = sigmoid -> f16 B-frags (C/D layout == B-frag layout)
#pragma unroll
        for (int mo = 0; mo < 4; ++mo) hb[mo] = sigpack(c1[mo]);

        // GEMM2: C2 = (-log2e W2^T) . H_new^T
        f32x4 c2[4];
        gemm4(aW2, hb, c2);
        // GEMM1 for NEXT step — independent of c2/score, overlaps sigma2+score
        gemm4(aW1, hb, c1);

        // prefetch next step's gathered rows (result used next iteration)
        half4 n0, n1, n2, n3;
        {
            int an = (a + 1 < A_) ? a + 1 : A_ - 1;   // last-iter prefetch discarded
            const _Float16* wp = wp_for(an);
            n0 = *(const half4*)(wp);
            n1 = *(const half4*)(wp + 16);
            n2 = *(const half4*)(wp + 32);
            n3 = *(const half4*)(wp + 48);
        }

        // Y -> f16; C/D layout == A-frag layout of Y(token x feat)
        half4 yh[4];
#pragma unroll
        for (int mo = 0; mo < 4; ++mo) yh[mo] = sigpack(c2[mo]);

        // score matrix S = Y . G^T via 4 MFMAs, two independent chains
        f32x4 za = {0.f, 0.f, 0.f, 0.f}, zb = {0.f, 0.f, 0.f, 0.f};
        za = __builtin_amdgcn_mfma_f32_16x16x16f16(yh[0], g0, za, 0, 0, 0);
        zb = __builtin_amdgcn_mfma_f32_16x16x16f16(yh[1], g1, zb, 0, 0, 0);
        za = __builtin_amdgcn_mfma_f32_16x16x16f16(yh[2], g2, za, 0, 0, 0);
        zb = __builtin_amdgcn_mfma_f32_16x16x16f16(yh[3], g3, zb, 0, 0, 0);
        f32x4 zs = za + zb;
        float val = s0 ? zs[0] : (s1 ? zs[1] : (s2 ? zs[2] : zs[3]));
        if (FIRST) val = (a < L) ? val : -1e9f;
        if (amDiag) scp[a] = val;

        g0 = n0; g1 = n1; g2 = n2; g3 = n3;
    }
    __syncthreads();

    // ---- softmax over a (48): 4 lanes per token, 12 scores each
    {
        int r = tid >> 2, s = tid & 3;
        float sc[12];
#pragma unroll
        for (int i = 0; i < 12; ++i) sc[i] = sm.sSc[r * SSTR + i * 4 + s];
        float m = sc[0];
#pragma unroll
        for (int i = 1; i < 12; ++i) m = fmaxf(m, sc[i]);
        m = fmaxf(m, __shfl_xor(m, 1));
        m = fmaxf(m, __shfl_xor(m, 2));
        float e[12]; float sum = 0.f;
#pragma unroll
        for (int i = 0; i < 12; ++i) { e[i] = __expf(sc[i] - m); sum += e[i]; }
        sum += __shfl_xor(sum, 1);
        sum += __shfl_xor(sum, 2);
        float inv = __builtin_amdgcn_rcpf(sum);
#pragma unroll
        for (int i = 0; i < 12; ++i) sm.sSc[r * SSTR + i * 4 + s] = e[i] * inv;
    }
    __syncthreads();

    // ---- ctx: 4 lanes per token, 16 features each (fp32 window)
    {
        int r = tid >> 2, fc = (tid & 3) * 16;
        int tgr = t0 + r;
        int Lr = min(A_, max(tgr, 1));
        float acc[16];
#pragma unroll
        for (int q = 0; q < 16; ++q) acc[q] = 0.f;
        for (int a = 0; a < A_; ++a) {
            float wgt = sm.sSc[r * SSTR + a];
            int j = tgr - Lr + a;
            if (FIRST) { if (j < 0) j = 0; }
            const float* wp = &sm.sWin[(j - t0 + 48) * WSTR + fc];
#pragma unroll
            for (int q = 0; q < 4; ++q) {
                float4 g = *(const float4*)(wp + q * 4);
                acc[q*4+0] += wgt * g.x; acc[q*4+1] += wgt * g.y;
                acc[q*4+2] += wgt * g.z; acc[q*4+3] += wgt * g.w;
            }
        }
        float* op = out + ((size_t)b * T_ + tgr) * F_ + fc;
#pragma unroll
        for (int q = 0; q < 4; ++q)
            *(float4*)(op + q * 4) = make_float4(acc[q*4], acc[q*4+1], acc[q*4+2], acc[q*4+3]);
    }
}

__global__ __launch_bounds__(256)
void ContextBlock_kernel(const float* __restrict__ he, const float* __restrict__ W1,
                         const float* __restrict__ W2, float* __restrict__ out)
{
    __shared__ Smem sm;                   // single 58.8 KB allocation, shared by both paths
    const int blk = blockIdx.x;
    if (blk < B_ * 31) {                  // 496 fast blocks: t0 >= 64, no clamps
        int b  = blk / 31;
        int t0 = ((blk % 31) + 1) * TOK;
        run_block<false>(sm, b, t0, he, W1, W2, out);
    } else {                              // 16 blocks with t0 == 0 (clamped path)
        int b = blk - B_ * 31;
        run_block<true>(sm, b, 0, he, W1, W2, out);
    }
}

extern "C" void kernel_launch(void* const* d_in, const int* in_sizes, int n_in,
                              void* d_out, int out_size, void* d_ws, size_t ws_size,
                              hipStream_t stream) {
    const float* he = (const float*)d_in[0];
    const float* W1 = (const float*)d_in[1];
    const float* W2 = (const float*)d_in[2];
    float* out = (float*)d_out;
    // attention_len (d_in[3]) fixed at 48 (baked as A_)
    hipLaunchKernelGGL(ContextBlock_kernel, dim3(512), dim3(256), 0, stream, he, W1, W2, out);
}

// Round 5
// 128.985 us; speedup vs baseline: 1.1277x; 1.1277x over previous
//
#include <hip/hip_runtime.h>

// Problem constants (fixed by setup_inputs)
#define B_   16
#define T_   2048
#define F_   64
#define A_   48
#define TOKB 16              // tokens per block (2 waves, feature-split pair)
#define NW   63              // window rows: t0-48 .. t0+14
#define HWS  72              // f16 window row stride (halves): 144B
#define PSTR 49              // partial-score row stride (floats)
#define LOG2E 1.4426950408889634f

typedef __attribute__((ext_vector_type(4))) _Float16 half4;  // MFMA 16x16x16 A/B frag
typedef __attribute__((ext_vector_type(8))) _Float16 half8;  // 16B LDS op
typedef __attribute__((ext_vector_type(2))) _Float16 h2;
typedef __attribute__((ext_vector_type(4))) float    f32x4;  // MFMA C/D frag

// Hardware-trans sigmoid (R3 lesson: polynomial/bit-trick versions issue MORE
// VALU cycles than v_exp_f32+v_rcp_f32). W pre-scaled by -log2e.
__device__ __forceinline__ float sigp(float c) {
    return __builtin_amdgcn_rcpf(1.0f + __builtin_amdgcn_exp2f(c));
}
__device__ __forceinline__ h2 pk2(float a, float b) {
    return __builtin_bit_cast(h2, __builtin_amdgcn_cvt_pkrtz(a, b));
}
__device__ __forceinline__ half4 sigpack(f32x4 c) {
    h2 lo = pk2(sigp(c[0]), sigp(c[1]));
    h2 hi = pk2(sigp(c[2]), sigp(c[3]));
    half4 h; h[0] = lo[0]; h[1] = lo[1]; h[2] = hi[0]; h[3] = hi[1];
    return h;
}

// 19.4 KB/block -> 8 blocks/CU -> 4 waves/SIMD (the point of this round).
struct Smem {
    alignas(16) _Float16 sWinH[NW * HWS];       // 9.07 KB f16 window (RNE)
    alignas(16) float    sPart[2][TOKB * PSTR]; // 6.27 KB per-wave partial scores
    alignas(16) _Float16 sXch[2 * 2 * 64 * 8];  // 4 KB H-half exchange, dbuf
};

// FIRST = t0 < 48 (tokens with L < 48: clamping + validity masks).
// Wave wv owns feature tiles mo = {2wv, 2wv+1} of GEMM1/GEMM2 and k-tiles
// {2wv, 2wv+1} of the score contraction; H halves exchanged via LDS.
//
// R4 bug fixed here: for FIRST blocks, invalid steps (a >= L) produced
// j = tg - L + a up to 47 -> window row j - t0 + 48 up to 95 > 62 = OOB LDS
// read -> garbage f16 (can be NaN) -> 0*NaN = NaN in the ctx epilogue.
// Fix: clamp j <= t0 + 14 (row <= 62). Valid steps have j <= tg-1 <= t0+14,
// so the clamp only affects masked/zero-weight steps, which may read any
// in-bounds row.
template<bool FIRST>
__device__ __forceinline__ void run_block(Smem& sm, int b, int t0,
                                          const float* __restrict__ he,
                                          const float* __restrict__ W1,
                                          const float* __restrict__ W2,
                                          float* __restrict__ out)
{
    const int tid = threadIdx.x;              // 0..127
    const float* __restrict__ heB = he + (size_t)b * T_ * F_;

    // ---- stage f16 window (RNE casts, not rtz: epilogue reads this too)
    for (int i = tid; i < NW * 16; i += 128) {
        int row = i >> 4, c4 = (i & 15) * 4;
        int g = t0 - 48 + row;
        if (!FIRST || g >= 0) {
            float4 v = *(const float4*)(heB + (size_t)g * F_ + c4);
            half4 h; h[0] = (_Float16)v.x; h[1] = (_Float16)v.y;
                     h[2] = (_Float16)v.z; h[3] = (_Float16)v.w;
            *(half4*)(&sm.sWinH[row * HWS + c4]) = h;
        }
    }

    const int lane = tid & 63;
    const int wv   = tid >> 6;           // 0 or 1: which feature half
    const int quad = lane >> 4;
    const int ml   = lane & 15;
    const int tg   = t0 + ml;            // this lane's token
    const int L    = min(A_, max(tg, 1));

    // ---- own A-frags: mo tiles {2wv, 2wv+1} only (half the registers)
    half4 aW1[2][4], aW2[2][4];
    for (int m = 0; m < 2; ++m) {
        int mo = wv * 2 + m;
        for (int kt = 0; kt < 4; ++kt) {
            half4 f1, f2;
#pragma unroll
            for (int j = 0; j < 4; ++j) {
                int k = kt * 16 + quad * 4 + j;
                f1[j] = (_Float16)(-LOG2E * W1[k * F_ + mo * 16 + ml]);
                f2[j] = (_Float16)(-LOG2E * W2[k * F_ + mo * 16 + ml]);
            }
            aW1[m][kt] = f1; aW2[m][kt] = f2;
        }
    }

    // ---- initial full H B-frags from global (both waves load all k-tiles)
    half4 hb[4];
#pragma unroll
    for (int kt = 0; kt < 4; ++kt) {
        float4 v = *(const float4*)(heB + (size_t)tg * F_ + kt * 16 + quad * 4);
        half4 h; h[0] = (_Float16)v.x; h[1] = (_Float16)v.y;
                 h[2] = (_Float16)v.z; h[3] = (_Float16)v.w;
        hb[kt] = h;
    }

    // ---- prologue GEMM1 (own half)
    f32x4 c1[2];
#pragma unroll
    for (int m = 0; m < 2; ++m) {
        f32x4 z = {0.f, 0.f, 0.f, 0.f};
#pragma unroll
        for (int kt = 0; kt < 4; ++kt)
            z = __builtin_amdgcn_mfma_f32_16x16x16f16(aW1[m][kt], hb[kt], z, 0, 0, 0);
        c1[m] = z;
    }

    __syncthreads();   // window staged

    const bool amDiag = (quad == (ml >> 2));
    const bool e0 = (ml & 3) == 0, e1 = (ml & 3) == 1, e2 = (ml & 3) == 2;
    float* pPart = &sm.sPart[wv][ml * PSTR];

    _Float16* xW0 = &sm.sXch[(0 * 2 + wv) * 512 + lane * 8];
    _Float16* xW1 = &sm.sXch[(1 * 2 + wv) * 512 + lane * 8];
    const _Float16* xR0 = &sm.sXch[(0 * 2 + (1 - wv)) * 512 + lane * 8];
    const _Float16* xR1 = &sm.sXch[(1 * 2 + (1 - wv)) * 512 + lane * 8];

    // fast-path g row for step a is (ml + a); this wave reads feats wv*32..+31
    const _Float16* __restrict__ wrow = &sm.sWinH[ml * HWS + wv * 32 + quad * 4];

    // ---- 48-step recurrence; 1 barrier/step, double-buffered H exchange
#pragma unroll 2
    for (int a = 0; a < A_; ++a) {
        const int p = a & 1;
        // own H_new half = sigmoid(c1)
        half4 h0 = sigpack(c1[0]);
        half4 h1 = sigpack(c1[1]);
        half8 w8 = {h0[0],h0[1],h0[2],h0[3], h1[0],h1[1],h1[2],h1[3]};
        *(half8*)(p ? xW1 : xW0) = w8;
        __syncthreads();                       // partner's half visible
        half8 r8 = *(const half8*)(p ? xR1 : xR0);
        half4 q0 = {r8[0], r8[1], r8[2], r8[3]};
        half4 q1 = {r8[4], r8[5], r8[6], r8[7]};
        if (wv == 0) { hb[0] = h0; hb[1] = h1; hb[2] = q0; hb[3] = q1; }
        else         { hb[0] = q0; hb[1] = q1; hb[2] = h0; hb[3] = h1; }

        // gathered-row B-frags for this wave's two score k-tiles
        const _Float16* gp;
        if (FIRST) {
            int j = tg - L + a;
            if (j < 0) j = 0;
            if (j > t0 + 14) j = t0 + 14;      // OOB fix: masked steps only
            gp = &sm.sWinH[(j + 48 - t0) * HWS + wv * 32 + quad * 4];
        } else gp = wrow + a * HWS;
        half4 gLo = *(const half4*)gp;
        half4 gHi = *(const half4*)(gp + 16);

        // GEMM2 (this step) + GEMM1 (next step), own halves: 16 MFMAs
        f32x4 c2[2];
#pragma unroll
        for (int m = 0; m < 2; ++m) {
            f32x4 z = {0.f, 0.f, 0.f, 0.f};
#pragma unroll
            for (int kt = 0; kt < 4; ++kt)
                z = __builtin_amdgcn_mfma_f32_16x16x16f16(aW2[m][kt], hb[kt], z, 0, 0, 0);
            c2[m] = z;
        }
#pragma unroll
        for (int m = 0; m < 2; ++m) {
            f32x4 z = {0.f, 0.f, 0.f, 0.f};
#pragma unroll
            for (int kt = 0; kt < 4; ++kt)
                z = __builtin_amdgcn_mfma_f32_16x16x16f16(aW1[m][kt], hb[kt], z, 0, 0, 0);
            c1[m] = z;
        }

        // own Y half -> partial score over k-tiles {2wv, 2wv+1}
        half4 y0 = sigpack(c2[0]);
        half4 y1 = sigpack(c2[1]);
        f32x4 zs = {0.f, 0.f, 0.f, 0.f};
        zs = __builtin_amdgcn_mfma_f32_16x16x16f16(y0, gLo, zs, 0, 0, 0);
        zs = __builtin_amdgcn_mfma_f32_16x16x16f16(y1, gHi, zs, 0, 0, 0);
        float val = e0 ? zs[0] : (e1 ? zs[1] : (e2 ? zs[2] : zs[3]));
        if (amDiag) pPart[a] = val;            // masking deferred to softmax
    }
    __syncthreads();

    // ---- softmax over a (48): 8 lanes per token, 6 scores each; sum partials
    {
        int r = tid >> 3, s = tid & 7;
        int Lr = min(A_, max(t0 + r, 1));
        float sc[6];
#pragma unroll
        for (int i = 0; i < 6; ++i) {
            int a = i * 8 + s;
            float v = sm.sPart[0][r * PSTR + a] + sm.sPart[1][r * PSTR + a];
            if (FIRST) v = (a < Lr) ? v : -1e9f;
            sc[i] = v;
        }
        float m = sc[0];
#pragma unroll
        for (int i = 1; i < 6; ++i) m = fmaxf(m, sc[i]);
        m = fmaxf(m, __shfl_xor(m, 1));
        m = fmaxf(m, __shfl_xor(m, 2));
        m = fmaxf(m, __shfl_xor(m, 4));
        float e[6]; float sum = 0.f;
#pragma unroll
        for (int i = 0; i < 6; ++i) { e[i] = __expf(sc[i] - m); sum += e[i]; }
        sum += __shfl_xor(sum, 1);
        sum += __shfl_xor(sum, 2);
        sum += __shfl_xor(sum, 4);
        float inv = __builtin_amdgcn_rcpf(sum);
#pragma unroll
        for (int i = 0; i < 6; ++i) sm.sPart[0][r * PSTR + i * 8 + s] = e[i] * inv;
    }
    __syncthreads();

    // ---- ctx: 8 lanes per token, 8 feats each; f16 window gather, f32 accum
    {
        int r = tid >> 3, fc = (tid & 7) * 8;
        int tgr = t0 + r;
        int Lr = min(A_, max(tgr, 1));
        float acc[8];
#pragma unroll
        for (int q = 0; q < 8; ++q) acc[q] = 0.f;
        for (int a = 0; a < A_; ++a) {
            float wgt = sm.sPart[0][r * PSTR + a];
            int j = tgr - Lr + a;
            if (FIRST) {
                if (j < 0) j = 0;
                if (j > t0 + 14) j = t0 + 14;  // OOB fix: wgt==0 steps only
            }
            half8 g = *(const half8*)(&sm.sWinH[(j - t0 + 48) * HWS + fc]);
#pragma unroll
            for (int q = 0; q < 8; ++q) acc[q] += wgt * (float)g[q];
        }
        float* op = out + ((size_t)b * T_ + tgr) * F_ + fc;
        *(float4*)(op)     = make_float4(acc[0], acc[1], acc[2], acc[3]);
        *(float4*)(op + 4) = make_float4(acc[4], acc[5], acc[6], acc[7]);
    }
}

__global__ __launch_bounds__(128, 4)
void ContextBlock_kernel(const float* __restrict__ he, const float* __restrict__ W1,
                         const float* __restrict__ W2, float* __restrict__ out)
{
    __shared__ Smem sm;
    const int blk = blockIdx.x;          // 2048 blocks: b = blk>>7, t0 = (blk&127)*16
    const int b  = blk >> 7;
    const int t0 = (blk & 127) << 4;
    if (t0 >= 48) run_block<false>(sm, b, t0, he, W1, W2, out);
    else          run_block<true >(sm, b, t0, he, W1, W2, out);
}

extern "C" void kernel_launch(void* const* d_in, const int* in_sizes, int n_in,
                              void* d_out, int out_size, void* d_ws, size_t ws_size,
                              hipStream_t stream) {
    const float* he = (const float*)d_in[0];
    const float* W1 = (const float*)d_in[1];
    const float* W2 = (const float*)d_in[2];
    float* out = (float*)d_out;
    // attention_len (d_in[3]) fixed at 48 (baked as A_)
    hipLaunchKernelGGL(ContextBlock_kernel, dim3(2048), dim3(128), 0, stream, he, W1, W2, out);
}